// Round 3
// baseline (252.776 us; speedup 1.0000x reference)
//
#include <hip/hip_runtime.h>

// Problem constants
#define BB 2
#define NRES 192
#define NATOMS 4
#define NN 768            // N = NRES*NATOMS
#define NODE_DIM 128
#define EDGE_DIM 64
#define NUM_RBF 32

// Output layout (float32 elements, concatenated flat in return order)
#define NODE_OFF   ((size_t)0)
#define EDGE_OFF   ((size_t)196608)                 // 2*768*128
#define COORDS_OFF ((size_t)(196608 + 75497472))    // + 2*768*768*64
#define MASK_OFF   ((size_t)(COORDS_OFF + 4608))    // + 2*768*3

__device__ __forceinline__ float silu(float x) { return x / (1.0f + expf(-x)); }

// ---------------------------------------------------------------------------
// Node kernel: one block (128 threads) per residue (B*NRES = 384 blocks).
// ---------------------------------------------------------------------------
__global__ __launch_bounds__(128) void node_kernel(
    const float* __restrict__ coords,
    const float* __restrict__ mut_mask,
    const float* __restrict__ atom_mask,
    const float* __restrict__ aa_emb,
    const float* __restrict__ atom_emb,
    const float* __restrict__ pos_emb,
    const float* __restrict__ aa_props,
    const float* __restrict__ mW1, const float* __restrict__ mb1,
    const float* __restrict__ mW2, const float* __restrict__ mb2,
    const float* __restrict__ nW1, const float* __restrict__ nb1,
    const float* __restrict__ nW2, const float* __restrict__ nb2,
    const int* __restrict__ wt_idx, const int* __restrict__ mut_idx,
    const int* __restrict__ res_idx,
    float* __restrict__ out)
{
    __shared__ float s_in[128];   // mut_in (124 used)
    __shared__ float s_h[128];    // hidden (64 or 128 used)
    __shared__ float s_res[96];   // res_feat (94 used)
    __shared__ float s_nin[128];  // node_in (126 used)

    const int blk = blockIdx.x;   // b*192 + r
    const int t = threadIdx.x;

    const int wt = wt_idx[blk];
    const int mu = mut_idx[blk];
    const float mm = mut_mask[blk];

    if (t < 32) { s_in[t] = aa_emb[wt * 32 + t]; s_in[32 + t] = aa_emb[mu * 32 + t]; }
    if (t < 30) { s_in[64 + t] = aa_props[wt * 30 + t]; s_in[94 + t] = aa_props[mu * 30 + t]; }
    __syncthreads();

    if (t < 64) {
        float acc = mb1[t];
        for (int k = 0; k < 124; ++k) acc += s_in[k] * mW1[k * 64 + t];
        s_h[t] = silu(acc);
    }
    __syncthreads();

    if (t < 32) {
        float acc = mb2[t];
        for (int k = 0; k < 64; ++k) acc += s_h[k] * mW2[k * 32 + t];
        s_res[62 + t] = acc * mm;
        s_res[t] = s_in[t];
    }
    if (t < 30) s_res[32 + t] = s_in[64 + t];
    __syncthreads();

    for (int a = 0; a < 4; ++a) {
        const int gn = blk * 4 + a;   // b*768 + n
        if (t < 94) s_nin[t] = s_res[t];
        else if (t < 110) s_nin[t] = atom_emb[a * 16 + (t - 94)];
        else if (t < 126) s_nin[t] = pos_emb[res_idx[gn] * 16 + (t - 110)];
        __syncthreads();

        float acc = nb1[t];
        for (int k = 0; k < 126; ++k) acc += s_nin[k] * nW1[k * 128 + t];
        float h = silu(acc);
        __syncthreads();
        s_h[t] = h;
        __syncthreads();

        float o = nb2[t];
        for (int k = 0; k < 128; ++k) o += s_h[k] * nW2[k * 128 + t];
        const float am = atom_mask[gn];
        out[NODE_OFF + (size_t)gn * 128 + t] = o * am;
        __syncthreads();
    }

    if (t < 12) out[COORDS_OFF + (size_t)blk * 12 + t] = coords[(size_t)blk * 12 + t];
    if (t < 4)  out[MASK_OFF + (size_t)blk * 4 + t]  = atom_mask[(size_t)blk * 4 + t];
}

// ---------------------------------------------------------------------------
// Edge kernel v3: one block (256 threads) per output row (b, i).
// Phase A: unconditional coalesced zero-fill of the whole 192KB row.
// Phase B: ballot-compact adjacent j's into LDS list; one lane per pair
//          computes the full 32->64->64 MLP with broadcast LDS weight reads,
//          then overwrites that pair's 256B sub-row.
// __syncthreads between phases drains vmcnt -> overwrite ordering is safe.
// ---------------------------------------------------------------------------
__global__ __launch_bounds__(256) void edge_kernel(
    const float* __restrict__ coords,
    const float* __restrict__ atom_mask,
    const float* __restrict__ eW1, const float* __restrict__ eb1,
    const float* __restrict__ eW2, const float* __restrict__ eb2,
    float* __restrict__ out)
{
    __shared__ float xs[NN], ys[NN], zs[NN], ms[NN];   // 12 KB
    __shared__ float sW1[NUM_RBF * 64];                // 8 KB
    __shared__ float sW2[64 * 64];                     // 16 KB
    __shared__ float sb1[64], sb2[64];                 // 0.5 KB
    __shared__ int s_list[NN];                         // 3 KB
    __shared__ int s_cnt;

    const int blk = blockIdx.x;
    const int b = blk / NN;
    const int i = blk % NN;
    const int t = threadIdx.x;
    const int lane = t & 63;

    // ---- stage LDS ----
    const float* cb = coords + (size_t)b * NN * 3;
    for (int n = t; n < NN; n += 256) {
        xs[n] = cb[n * 3 + 0];
        ys[n] = cb[n * 3 + 1];
        zs[n] = cb[n * 3 + 2];
        ms[n] = atom_mask[(size_t)b * NN + n];
    }
    for (int k = t; k < NUM_RBF * 64; k += 256) sW1[k] = eW1[k];
    for (int k = t; k < 64 * 64; k += 256)      sW2[k] = eW2[k];
    if (t < 64) { sb1[t] = eb1[t]; sb2[t] = eb2[t]; }
    if (t == 0) s_cnt = 0;
    __syncthreads();

    float* rowp = out + EDGE_OFF + ((size_t)b * NN + i) * (size_t)NN * EDGE_DIM;

    // ---- Phase A: stream zeros over the whole row (196,608 B) ----
    {
        uint4 z4 = make_uint4(0u, 0u, 0u, 0u);
        uint4* zp = (uint4*)rowp;                      // 12288 uint4
        #pragma unroll 4
        for (int q = t; q < NN * EDGE_DIM / 4; q += 256) zp[q] = z4;
    }

    // ---- adjacency + ballot compaction (overlaps store drain) ----
    const float xi = xs[i], yi = ys[i], zi = zs[i], mi = ms[i];
    for (int r = 0; r < 3; ++r) {
        const int j = t + r * 256;
        const float dx = xi - xs[j];
        const float dy = yi - ys[j];
        const float dz = zi - zs[j];
        const float d2 = dx * dx + dy * dy + dz * dz + 1e-8f;
        const float mprod = mi * ms[j];
        const bool adj = (d2 <= 7.5f * 7.5f) && (j != i) && (mprod != 0.0f);
        const unsigned long long bal = __ballot(adj);
        const int lofs = __popcll(bal & ((1ull << lane) - 1ull));
        int base = 0;
        if (lane == 0 && bal) base = atomicAdd(&s_cnt, __popcll(bal));
        base = __shfl(base, 0);
        if (adj) s_list[base + lofs] = j;
    }
    __syncthreads();   // drains Phase-A stores (vmcnt(0)) + publishes list

    // ---- Phase B: one lane per adjacent pair ----
    const int cnt = s_cnt;
    for (int base = 0; base < cnt; base += 256) {
        const int idx = base + t;
        if (idx < cnt) {
            const int j = s_list[idx];
            const float dx = xi - xs[j];
            const float dy = yi - ys[j];
            const float dz = zi - zs[j];
            const float d = sqrtf(dx * dx + dy * dy + dz * dz + 1e-8f);
            const float mf = mi * ms[j];

            float rbf[NUM_RBF];
            #pragma unroll
            for (int k = 0; k < NUM_RBF; ++k) {
                const float dd = d - (float)k * (20.0f / 31.0f);
                rbf[k] = expf(-(dd * dd) / 0.78125f);   // 2*gamma^2, gamma=0.625
            }

            float o[EDGE_DIM];
            #pragma unroll
            for (int c = 0; c < EDGE_DIM; c += 4) {
                const float4 bb4 = *(const float4*)&sb2[c];
                o[c] = bb4.x; o[c + 1] = bb4.y; o[c + 2] = bb4.z; o[c + 3] = bb4.w;
            }

            for (int h = 0; h < 64; ++h) {             // rolled; inner unrolled
                float acc = sb1[h];
                #pragma unroll
                for (int k = 0; k < NUM_RBF; ++k) acc += rbf[k] * sW1[k * 64 + h];
                const float hv = silu(acc);
                #pragma unroll
                for (int c = 0; c < EDGE_DIM; c += 4) {
                    const float4 w4 = *(const float4*)&sW2[h * 64 + c];
                    o[c]     += hv * w4.x;
                    o[c + 1] += hv * w4.y;
                    o[c + 2] += hv * w4.z;
                    o[c + 3] += hv * w4.w;
                }
            }

            float* pp = rowp + (size_t)j * EDGE_DIM;
            #pragma unroll
            for (int q = 0; q < EDGE_DIM / 4; ++q) {
                ((float4*)pp)[q] = make_float4(o[4 * q] * mf, o[4 * q + 1] * mf,
                                               o[4 * q + 2] * mf, o[4 * q + 3] * mf);
            }
        }
    }
}

extern "C" void kernel_launch(void* const* d_in, const int* in_sizes, int n_in,
                              void* d_out, int out_size, void* d_ws, size_t ws_size,
                              hipStream_t stream) {
    const float* coords    = (const float*)d_in[0];
    const float* mut_mask  = (const float*)d_in[1];
    const float* atom_mask = (const float*)d_in[2];
    const float* aa_emb    = (const float*)d_in[3];
    const float* atom_emb  = (const float*)d_in[4];
    const float* pos_emb   = (const float*)d_in[5];
    const float* aa_props  = (const float*)d_in[6];
    const float* mut_W1    = (const float*)d_in[7];
    const float* mut_b1    = (const float*)d_in[8];
    const float* mut_W2    = (const float*)d_in[9];
    const float* mut_b2    = (const float*)d_in[10];
    const float* node_W1   = (const float*)d_in[11];
    const float* node_b1   = (const float*)d_in[12];
    const float* node_W2   = (const float*)d_in[13];
    const float* node_b2   = (const float*)d_in[14];
    const float* edge_W1   = (const float*)d_in[15];
    const float* edge_b1   = (const float*)d_in[16];
    const float* edge_W2   = (const float*)d_in[17];
    const float* edge_b2   = (const float*)d_in[18];
    const int* wt_indices  = (const int*)d_in[19];
    const int* mut_indices = (const int*)d_in[20];
    const int* res_indices = (const int*)d_in[21];

    float* out = (float*)d_out;

    node_kernel<<<BB * NRES, 128, 0, stream>>>(
        coords, mut_mask, atom_mask, aa_emb, atom_emb, pos_emb, aa_props,
        mut_W1, mut_b1, mut_W2, mut_b2, node_W1, node_b1, node_W2, node_b2,
        wt_indices, mut_indices, res_indices, out);

    edge_kernel<<<BB * NN, 256, 0, stream>>>(
        coords, atom_mask, edge_W1, edge_b1, edge_W2, edge_b2, out);
}

// Round 4
// 140.265 us; speedup vs baseline: 1.8021x; 1.8021x over previous
//
#include <hip/hip_runtime.h>

// Problem constants
#define BB 2
#define NRES 192
#define NATOMS 4
#define NN 768            // N = NRES*NATOMS
#define NODE_DIM 128
#define EDGE_DIM 64
#define NUM_RBF 32
#define NROWS (BB * NN)   // 1536

// Output layout (float32 elements, concatenated flat in return order)
#define NODE_OFF   ((size_t)0)
#define EDGE_OFF   ((size_t)196608)                 // 2*768*128
#define COORDS_OFF ((size_t)(196608 + 75497472))    // + 2*768*768*64
#define MASK_OFF   ((size_t)(COORDS_OFF + 4608))    // + 2*768*3

// Workspace layout (ints): cnts[NROWS], then lists[NROWS][NN]
#define WS_NEEDED ((size_t)(NROWS + (size_t)NROWS * NN) * 4)

__device__ __forceinline__ float silu(float x) { return x / (1.0f + expf(-x)); }

// ---------------------------------------------------------------------------
// Node kernel: one block (128 threads) per residue (B*NRES = 384 blocks).
// ---------------------------------------------------------------------------
__global__ __launch_bounds__(128) void node_kernel(
    const float* __restrict__ coords,
    const float* __restrict__ mut_mask,
    const float* __restrict__ atom_mask,
    const float* __restrict__ aa_emb,
    const float* __restrict__ atom_emb,
    const float* __restrict__ pos_emb,
    const float* __restrict__ aa_props,
    const float* __restrict__ mW1, const float* __restrict__ mb1,
    const float* __restrict__ mW2, const float* __restrict__ mb2,
    const float* __restrict__ nW1, const float* __restrict__ nb1,
    const float* __restrict__ nW2, const float* __restrict__ nb2,
    const int* __restrict__ wt_idx, const int* __restrict__ mut_idx,
    const int* __restrict__ res_idx,
    float* __restrict__ out)
{
    __shared__ float s_in[128];   // mut_in (124 used)
    __shared__ float s_h[128];    // hidden (64 or 128 used)
    __shared__ float s_res[96];   // res_feat (94 used)
    __shared__ float s_nin[128];  // node_in (126 used)

    const int blk = blockIdx.x;   // b*192 + r
    const int t = threadIdx.x;

    const int wt = wt_idx[blk];
    const int mu = mut_idx[blk];
    const float mm = mut_mask[blk];

    if (t < 32) { s_in[t] = aa_emb[wt * 32 + t]; s_in[32 + t] = aa_emb[mu * 32 + t]; }
    if (t < 30) { s_in[64 + t] = aa_props[wt * 30 + t]; s_in[94 + t] = aa_props[mu * 30 + t]; }
    __syncthreads();

    if (t < 64) {
        float acc = mb1[t];
        for (int k = 0; k < 124; ++k) acc += s_in[k] * mW1[k * 64 + t];
        s_h[t] = silu(acc);
    }
    __syncthreads();

    if (t < 32) {
        float acc = mb2[t];
        for (int k = 0; k < 64; ++k) acc += s_h[k] * mW2[k * 32 + t];
        s_res[62 + t] = acc * mm;
        s_res[t] = s_in[t];
    }
    if (t < 30) s_res[32 + t] = s_in[64 + t];
    __syncthreads();

    for (int a = 0; a < 4; ++a) {
        const int gn = blk * 4 + a;   // b*768 + n
        if (t < 94) s_nin[t] = s_res[t];
        else if (t < 110) s_nin[t] = atom_emb[a * 16 + (t - 94)];
        else if (t < 126) s_nin[t] = pos_emb[res_idx[gn] * 16 + (t - 110)];
        __syncthreads();

        float acc = nb1[t];
        for (int k = 0; k < 126; ++k) acc += s_nin[k] * nW1[k * 128 + t];
        float h = silu(acc);
        __syncthreads();
        s_h[t] = h;
        __syncthreads();

        float o = nb2[t];
        for (int k = 0; k < 128; ++k) o += s_h[k] * nW2[k * 128 + t];
        const float am = atom_mask[gn];
        out[NODE_OFF + (size_t)gn * 128 + t] = o * am;
        __syncthreads();
    }

    if (t < 12) out[COORDS_OFF + (size_t)blk * 12 + t] = coords[(size_t)blk * 12 + t];
    if (t < 4)  out[MASK_OFF + (size_t)blk * 4 + t]  = atom_mask[(size_t)blk * 4 + t];
}

// ---------------------------------------------------------------------------
// pair_kernel: one block (256 threads) per row (b,i). Ballot-compacts the
// adjacent j's into an LDS list, then writes cnt + list to d_ws (per-row
// segment, no global atomics).
// ---------------------------------------------------------------------------
__global__ __launch_bounds__(256) void pair_kernel(
    const float* __restrict__ coords,
    const float* __restrict__ atom_mask,
    int* __restrict__ ws)
{
    __shared__ int s_list[NN];
    __shared__ int s_cnt;

    const int row = blockIdx.x;        // b*NN + i
    const int b = row / NN;
    const int i = row % NN;
    const int t = threadIdx.x;
    const int lane = t & 63;

    if (t == 0) s_cnt = 0;
    __syncthreads();

    const float* cb = coords + (size_t)b * NN * 3;
    const float* mb = atom_mask + (size_t)b * NN;
    const float xi = cb[i * 3 + 0], yi = cb[i * 3 + 1], zi = cb[i * 3 + 2];
    const float mi = mb[i];

    for (int r = 0; r < 3; ++r) {
        const int j = t + r * 256;
        const float dx = xi - cb[j * 3 + 0];
        const float dy = yi - cb[j * 3 + 1];
        const float dz = zi - cb[j * 3 + 2];
        const float d2 = dx * dx + dy * dy + dz * dz + 1e-8f;
        const float mprod = mi * mb[j];
        const bool adj = (d2 <= 7.5f * 7.5f) && (j != i) && (mprod != 0.0f);
        const unsigned long long bal = __ballot(adj);
        const int lofs = __popcll(bal & ((1ull << lane) - 1ull));
        int base = 0;
        if (lane == 0 && bal) base = atomicAdd(&s_cnt, __popcll(bal));
        base = __shfl(base, 0);
        if (adj) s_list[base + lofs] = j;
    }
    __syncthreads();

    const int cnt = s_cnt;
    if (t == 0) ws[row] = cnt;
    int* listp = ws + NROWS + (size_t)row * NN;
    for (int q = t; q < cnt; q += 256) listp[q] = s_list[q];
}

// ---------------------------------------------------------------------------
// mlp_kernel: one block (256 threads) per row. One lane per adjacent pair,
// full 32->64->64 MLP with wave-uniform weight loads (no LDS).
// Overwrites the pre-zeroed 256B sub-rows.
// ---------------------------------------------------------------------------
__global__ __launch_bounds__(256) void mlp_kernel(
    const float* __restrict__ coords,
    const float* __restrict__ atom_mask,
    const float* __restrict__ eW1, const float* __restrict__ eb1,
    const float* __restrict__ eW2, const float* __restrict__ eb2,
    const int* __restrict__ ws,
    float* __restrict__ out)
{
    const int row = blockIdx.x;        // b*NN + i
    const int cnt = ws[row];
    if (cnt == 0) return;

    const int b = row / NN;
    const int i = row % NN;
    const int t = threadIdx.x;

    const float* cb = coords + (size_t)b * NN * 3;
    const float* mb = atom_mask + (size_t)b * NN;
    const float xi = cb[i * 3 + 0], yi = cb[i * 3 + 1], zi = cb[i * 3 + 2];
    const float mi = mb[i];
    const int* listp = ws + NROWS + (size_t)row * NN;
    float* rowp = out + EDGE_OFF + (size_t)row * (size_t)NN * EDGE_DIM;

    for (int idx = t; idx < cnt; idx += 256) {
        const int j = listp[idx];
        const float dx = xi - cb[j * 3 + 0];
        const float dy = yi - cb[j * 3 + 1];
        const float dz = zi - cb[j * 3 + 2];
        const float d = sqrtf(dx * dx + dy * dy + dz * dz + 1e-8f);
        const float mf = mi * mb[j];

        float rbf[NUM_RBF];
        #pragma unroll
        for (int k = 0; k < NUM_RBF; ++k) {
            const float dd = d - (float)k * (20.0f / 31.0f);
            rbf[k] = expf(-(dd * dd) / 0.78125f);   // 2*gamma^2, gamma=0.625
        }

        float o[EDGE_DIM];
        #pragma unroll
        for (int c = 0; c < EDGE_DIM; c += 4) {
            const float4 bb4 = *(const float4*)&eb2[c];
            o[c] = bb4.x; o[c + 1] = bb4.y; o[c + 2] = bb4.z; o[c + 3] = bb4.w;
        }

        for (int h = 0; h < 64; ++h) {             // uniform weight indices
            float acc = eb1[h];
            #pragma unroll
            for (int k = 0; k < NUM_RBF; ++k) acc += rbf[k] * eW1[k * 64 + h];
            const float hv = silu(acc);
            #pragma unroll
            for (int c = 0; c < EDGE_DIM; c += 4) {
                const float4 w4 = *(const float4*)&eW2[h * 64 + c];
                o[c]     += hv * w4.x;
                o[c + 1] += hv * w4.y;
                o[c + 2] += hv * w4.z;
                o[c + 3] += hv * w4.w;
            }
        }

        float* pp = rowp + (size_t)j * EDGE_DIM;
        #pragma unroll
        for (int q = 0; q < EDGE_DIM / 4; ++q) {
            ((float4*)pp)[q] = make_float4(o[4 * q] * mf, o[4 * q + 1] * mf,
                                           o[4 * q + 2] * mf, o[4 * q + 3] * mf);
        }
    }
}

// ---------------------------------------------------------------------------
// Fallback fused edge kernel (R2 design) if ws_size is too small.
// ---------------------------------------------------------------------------
__global__ __launch_bounds__(256) void edge_fused_kernel(
    const float* __restrict__ coords,
    const float* __restrict__ atom_mask,
    const float* __restrict__ eW1, const float* __restrict__ eb1,
    const float* __restrict__ eW2, const float* __restrict__ eb2,
    float* __restrict__ out)
{
    __shared__ float xs[NN], ys[NN], zs[NN], ms[NN];
    __shared__ float W1[NUM_RBF * 64];
    __shared__ float W2[64 * 64];
    __shared__ float b1[64], b2[64];

    const int blk = blockIdx.x;
    const int b = blk / NN;
    const int i = blk % NN;
    const int t = threadIdx.x;

    const float* cb = coords + (size_t)b * NN * 3;
    for (int n = t; n < NN; n += 256) {
        xs[n] = cb[n * 3 + 0];
        ys[n] = cb[n * 3 + 1];
        zs[n] = cb[n * 3 + 2];
        ms[n] = atom_mask[(size_t)b * NN + n];
    }
    for (int k = t; k < NUM_RBF * 64; k += 256) W1[k] = eW1[k];
    for (int k = t; k < 64 * 64; k += 256)      W2[k] = eW2[k];
    if (t < 64) { b1[t] = eb1[t]; b2[t] = eb2[t]; }
    __syncthreads();

    const int lane = t & 63;
    const int wv = t >> 6;
    const float xi = xs[i], yi = ys[i], zi = zs[i], mi = ms[i];
    float* rowp = out + EDGE_OFF + ((size_t)b * NN + i) * (size_t)NN * EDGE_DIM;

    for (int g = wv; g < NN / 8; g += 4) {
        const int j0 = g * 8;
        const int jj = j0 + (lane & 7);
        const float dx = xi - xs[jj];
        const float dy = yi - ys[jj];
        const float dz = zi - zs[jj];
        const float dist = sqrtf(dx * dx + dy * dy + dz * dz + 1e-8f);
        const float mprod = mi * ms[jj];
        const bool adj = (dist <= 7.5f) && (jj != i) && (mprod != 0.0f);
        const unsigned long long bal = __ballot(adj && (lane < 8));
        float* gp = rowp + (size_t)j0 * EDGE_DIM;

        if (bal == 0ULL) {
            ((uint4*)gp)[lane] = make_uint4(0u, 0u, 0u, 0u);
            ((uint4*)gp)[lane + 64] = make_uint4(0u, 0u, 0u, 0u);
        } else {
            for (int p = 0; p < 8; ++p) {
                float* pp = gp + p * EDGE_DIM;
                if ((bal >> p) & 1ULL) {
                    const float d = __shfl(dist, p);
                    const float mf = __shfl(mprod, p);
                    const float ck = (float)(lane & 31) * (20.0f / 31.0f);
                    const float dd = d - ck;
                    const float my_r = expf(-(dd * dd) / 0.78125f);
                    float acc = b1[lane];
                    #pragma unroll
                    for (int k = 0; k < 32; ++k) {
                        const float rk = __shfl(my_r, k);
                        acc += rk * W1[k * 64 + lane];
                    }
                    const float h = silu(acc);
                    float o = b2[lane];
                    for (int hh = 0; hh < 64; ++hh) {
                        const float hv = __shfl(h, hh);
                        o += hv * W2[hh * 64 + lane];
                    }
                    pp[lane] = o * mf;
                } else {
                    ((unsigned int*)pp)[lane] = 0u;
                }
            }
        }
    }
}

extern "C" void kernel_launch(void* const* d_in, const int* in_sizes, int n_in,
                              void* d_out, int out_size, void* d_ws, size_t ws_size,
                              hipStream_t stream) {
    const float* coords    = (const float*)d_in[0];
    const float* mut_mask  = (const float*)d_in[1];
    const float* atom_mask = (const float*)d_in[2];
    const float* aa_emb    = (const float*)d_in[3];
    const float* atom_emb  = (const float*)d_in[4];
    const float* pos_emb   = (const float*)d_in[5];
    const float* aa_props  = (const float*)d_in[6];
    const float* mut_W1    = (const float*)d_in[7];
    const float* mut_b1    = (const float*)d_in[8];
    const float* mut_W2    = (const float*)d_in[9];
    const float* mut_b2    = (const float*)d_in[10];
    const float* node_W1   = (const float*)d_in[11];
    const float* node_b1   = (const float*)d_in[12];
    const float* node_W2   = (const float*)d_in[13];
    const float* node_b2   = (const float*)d_in[14];
    const float* edge_W1   = (const float*)d_in[15];
    const float* edge_b1   = (const float*)d_in[16];
    const float* edge_W2   = (const float*)d_in[17];
    const float* edge_b2   = (const float*)d_in[18];
    const int* wt_indices  = (const int*)d_in[19];
    const int* mut_indices = (const int*)d_in[20];
    const int* res_indices = (const int*)d_in[21];

    float* out = (float*)d_out;

    if (ws_size >= WS_NEEDED) {
        // 1) bulk zero of the whole output at blit rate
        hipMemsetAsync(d_out, 0, (size_t)out_size * sizeof(float), stream);
        // 2) node features (+ coords/mask passthrough)
        node_kernel<<<BB * NRES, 128, 0, stream>>>(
            coords, mut_mask, atom_mask, aa_emb, atom_emb, pos_emb, aa_props,
            mut_W1, mut_b1, mut_W2, mut_b2, node_W1, node_b1, node_W2, node_b2,
            wt_indices, mut_indices, res_indices, out);
        // 3) adjacency lists
        pair_kernel<<<NROWS, 256, 0, stream>>>(coords, atom_mask, (int*)d_ws);
        // 4) sparse edge MLP overwrite
        mlp_kernel<<<NROWS, 256, 0, stream>>>(
            coords, atom_mask, edge_W1, edge_b1, edge_W2, edge_b2,
            (const int*)d_ws, out);
    } else {
        node_kernel<<<BB * NRES, 128, 0, stream>>>(
            coords, mut_mask, atom_mask, aa_emb, atom_emb, pos_emb, aa_props,
            mut_W1, mut_b1, mut_W2, mut_b2, node_W1, node_b1, node_W2, node_b2,
            wt_indices, mut_indices, res_indices, out);
        edge_fused_kernel<<<NROWS, 256, 0, stream>>>(
            coords, atom_mask, edge_W1, edge_b1, edge_W2, edge_b2, out);
    }
}